// Round 5
// baseline (129.504 us; speedup 1.0000x reference)
//
#include <hip/hip_runtime.h>
#include <hip/hip_fp16.h>
#include <math.h>

#define NN 512
#define NODE_D 256
#define EDGE_D 128
#define HN 8

#define SCALAR_SCALE 0.14433756729740643f   // (3*16)^-0.5
#define POINT_SCALE  0.13608276348795434f   // (3*4*4.5)^-0.5
#define PAIR_SCALE   0.5773502691896258f    // 3^-0.5

// workspace float offsets
#define OFF_QS   0            // 512x128
#define OFF_KS   65536        // 512x128
#define OFF_VS   131072       // 512x128
#define OFF_VP   196608       // 512x96
#define OFF_QCAT 245760       // 512x288
#define OFF_KCAT 393216       // 512x288
#define OFF_FEAT 540672       // 512x1280
#define OFF_PRAW OFF_FEAT     // 512x288 alias; consumed by k_rot2 before feat written
#define OFF_LG16 1196032      // 512*512*8 halfs = 1048576 float-equiv
#define OFF_W    2244608      // 512*512*8 fp32 normalized attn weights (8MB)
#define OFF_RP   4341760      // res_pair partials: 512 i x 4 jt x 1024 (16MB)
#define OFF_OUTP 6438912      // 4*512*256 floats
// total ws = 6963200 floats = 27.9 MB

// ---------------------------------------------------------------------------
// Kernel A1: Y(512x672) = node @ [Wsq|Wsk|Wsv|Wpq|Wpk|Wpv]. grid (16,21).
// ---------------------------------------------------------------------------
__global__ __launch_bounds__(256) void k_projgemm(
    const float* __restrict__ node,
    const float* __restrict__ Wsq, const float* __restrict__ Wsk, const float* __restrict__ Wsv,
    const float* __restrict__ Wpq, const float* __restrict__ Wpk, const float* __restrict__ Wpv,
    float* __restrict__ ws)
{
  __shared__ float As[32 * 33];
  __shared__ float Bs[32 * 36];
  const int t = threadIdx.x;
  const int it = blockIdx.x;
  const int ct = blockIdx.y;

  const float* W; int ncol, col0; float* dst; int ldd, dcol0;
  if (ct < 12) {
    int a = ct >> 2;
    W = (a == 0) ? Wsq : (a == 1) ? Wsk : Wsv;
    ncol = 128; col0 = (ct & 3) * 32;
    dst = ws + ((a == 0) ? OFF_QS : (a == 1) ? OFF_KS : OFF_VS);
    ldd = 128; dcol0 = col0;
  } else {
    int p = ct - 12;
    int a = p / 3, cc = p % 3;
    W = (a == 0) ? Wpq : (a == 1) ? Wpk : Wpv;
    ncol = 96; col0 = cc * 32;
    dst = ws + OFF_PRAW;
    ldd = 288; dcol0 = a * 96 + cc * 32;
  }

  const int row = t & 31, cb = (t >> 5) * 4;
  float4 acc = {0.f, 0.f, 0.f, 0.f};

  for (int kt = 0; kt < 8; ++kt) {
    __syncthreads();
    #pragma unroll
    for (int q = 0; q < 4; ++q) {
      int f = t + q * 256; int r = f >> 5, c = f & 31;
      As[r * 33 + c] = node[(size_t)(it * 32 + r) * 256 + kt * 32 + c];
      Bs[r * 36 + c] = W[(size_t)(kt * 32 + r) * ncol + col0 + c];
    }
    __syncthreads();
    #pragma unroll
    for (int k = 0; k < 32; ++k) {
      float a = As[row * 33 + k];
      float4 b = *(const float4*)&Bs[k * 36 + cb];
      acc.x += a * b.x; acc.y += a * b.y; acc.z += a * b.z; acc.w += a * b.w;
    }
  }
  *(float4*)&dst[(size_t)(it * 32 + row) * ldd + dcol0 + cb] = acc;
}

// ---------------------------------------------------------------------------
// Kernel A2: rotate/translate points; build Qcat/Kcat (scales folded); vp out.
// ---------------------------------------------------------------------------
__global__ __launch_bounds__(256) void k_rot2(
    const float* __restrict__ rotm, const float* __restrict__ trans,
    const float* __restrict__ pw_in, const float* __restrict__ bpb,
    float* __restrict__ ws)
{
  __shared__ float p_l[4][288];
  __shared__ float r_l[4][288];
  __shared__ float q2_l[4][8];
  __shared__ float k2_l[4][8];
  __shared__ float pw_l[8];
  __shared__ float bpb_l[8];
  const int t = threadIdx.x;
  const int n0 = blockIdx.x * 4;
  const float* praw = ws + OFF_PRAW;
  const float* qs_g = ws + OFF_QS;
  const float* ks_g = ws + OFF_KS;

  if (t < 8) {
    float x = pw_in[t];
    pw_l[t] = 0.5f * POINT_SCALE * logf(1.0f + expf(x));
    bpb_l[t] = bpb[t];
  }
  for (int idx = t; idx < 1152; idx += 256) {
    int row = idx / 288, rem = idx % 288;
    p_l[row][rem] = praw[(size_t)(n0 + row) * 288 + rem];
  }
  __syncthreads();

  for (int idx = t; idx < 1152; idx += 256) {
    int row = idx / 288, rem = idx % 288;
    int a = rem / 96, col = rem % 96;
    int rr = col % 3;
    int n = n0 + row;
    const float* R = rotm + (size_t)(n * 3 + rr) * 3;
    const float* P = &p_l[row][a * 96 + (col - rr)];
    float val = P[0] * R[0] + P[1] * R[1] + P[2] * R[2] + trans[n * 3 + rr];
    r_l[row][a * 96 + col] = val;
    if (a == 2) (ws + OFF_VP)[(size_t)n * 96 + col] = val;
  }
  __syncthreads();

  if (t < 64) {
    int row = t >> 4, rem = t & 15;
    int which = rem >> 3, h = rem & 7;
    const float* src = &r_l[row][which * 96 + h * 12];
    float s = 0.f;
    #pragma unroll
    for (int m = 0; m < 12; ++m) s += src[m] * src[m];
    if (which == 0) q2_l[row][h] = s; else k2_l[row][h] = s;
  }
  __syncthreads();

  for (int idx = t; idx < 2304; idx += 256) {
    int side = idx >= 1152;
    int per = idx - side * 1152;
    int row = per / 288, s = per % 288;
    int h = s / 36, e = s % 36;
    int n = n0 + row;
    float val;
    if (!side) {
      val = (e < 16) ? qs_g[(size_t)n * 128 + h * 16 + e] * SCALAR_SCALE
          : (e < 28) ? 2.0f * pw_l[h] * r_l[row][h * 12 + (e - 16)]
          : (e == 32) ? -pw_l[h]
          : (e == 33) ? (bpb_l[h] * PAIR_SCALE - pw_l[h] * q2_l[row][h])
          : 0.f;
      (ws + OFF_QCAT)[(size_t)n * 288 + s] = val;
    } else {
      val = (e < 16) ? ks_g[(size_t)n * 128 + h * 16 + e]
          : (e < 28) ? r_l[row][96 + h * 12 + (e - 16)]
          : (e == 32) ? k2_l[row][h]
          : (e == 33) ? 1.f
          : 0.f;
      (ws + OFF_KCAT)[(size_t)n * 288 + s] = val;
    }
  }
}

// ---------------------------------------------------------------------------
// Kernel B1a: non-pair logits = batched GEMM lg[i,j,h] = dot36(Qcat,Kcat).
// ---------------------------------------------------------------------------
__global__ __launch_bounds__(256) void k_S(
    const float* __restrict__ ws_c, __half* __restrict__ lg16)
{
  __shared__ float4 Qt[32 * 36];
  __shared__ float4 Kt[32 * 37];
  __shared__ __half lgst[32 * 32 * 8];
  const int t = threadIdx.x;
  const int it = blockIdx.x, jt = blockIdx.y;
  const float* Qc = ws_c + OFF_QCAT;
  const float* Kc = ws_c + OFF_KCAT;
  const int ti = t >> 4, tj = t & 15;

  for (int hg = 0; hg < 2; ++hg) {
    __syncthreads();
    for (int f = t; f < 1152; f += 256) {
      int row = f / 36, c = f % 36;
      Qt[row * 36 + c] = *(const float4*)&Qc[(size_t)(it * 32 + row) * 288 + hg * 144 + c * 4];
      Kt[row * 37 + c] = *(const float4*)&Kc[(size_t)(jt * 32 + row) * 288 + hg * 144 + c * 4];
    }
    __syncthreads();

    float acc[2][2][4];
    #pragma unroll
    for (int a = 0; a < 2; ++a)
      #pragma unroll
      for (int b = 0; b < 2; ++b)
        #pragma unroll
        for (int h = 0; h < 4; ++h) acc[a][b][h] = 0.f;

    for (int c = 0; c < 9; ++c) {
      #pragma unroll
      for (int hh = 0; hh < 4; ++hh) {
        float4 q0 = Qt[(2 * ti + 0) * 36 + hh * 9 + c];
        float4 q1 = Qt[(2 * ti + 1) * 36 + hh * 9 + c];
        float4 k0 = Kt[(2 * tj + 0) * 37 + hh * 9 + c];
        float4 k1 = Kt[(2 * tj + 1) * 37 + hh * 9 + c];
        acc[0][0][hh] += q0.x * k0.x + q0.y * k0.y + q0.z * k0.z + q0.w * k0.w;
        acc[0][1][hh] += q0.x * k1.x + q0.y * k1.y + q0.z * k1.z + q0.w * k1.w;
        acc[1][0][hh] += q1.x * k0.x + q1.y * k0.y + q1.z * k0.z + q1.w * k0.w;
        acc[1][1][hh] += q1.x * k1.x + q1.y * k1.y + q1.z * k1.z + q1.w * k1.w;
      }
    }
    #pragma unroll
    for (int a = 0; a < 2; ++a)
      #pragma unroll
      for (int b = 0; b < 2; ++b)
        #pragma unroll
        for (int hh = 0; hh < 4; ++hh)
          lgst[((2 * ti + a) * 32 + (2 * tj + b)) * 8 + hg * 4 + hh] = __float2half(acc[a][b][hh]);
  }
  __syncthreads();

  for (int f = t; f < 1024; f += 256) {
    int il = f >> 5, jl = f & 31;
    float4 v = *(const float4*)&lgst[(il * 32 + jl) * 8];
    *(float4*)&lg16[((size_t)(it * 32 + il) * 512 + jt * 32 + jl) * 8] = v;
  }
}

// ---------------------------------------------------------------------------
// Kernel B1b: pair logits, coalesced edge stream. grid (4 jt, 512 i).
// ---------------------------------------------------------------------------
static __device__ inline __half2 shfl_xor_h2(__half2 h, int m) {
  int v = __builtin_bit_cast(int, h);
  v = __shfl_xor(v, m);
  return __builtin_bit_cast(__half2, v);
}

__global__ __launch_bounds__(256) void k_pair(
    const float* __restrict__ edge, const float* __restrict__ Wpb,
    __half* __restrict__ lg16)
{
  const int t = threadIdx.x;
  const int jt = blockIdx.x, i = blockIdx.y;
  const int l = t & 63, w = t >> 6;
  const int rg = (l >> 4) & 3, sub = l & 15;

  float wv[4][2][8];
  #pragma unroll
  for (int k = 0; k < 4; ++k)
    #pragma unroll
    for (int c = 0; c < 2; ++c)
      #pragma unroll
      for (int h = 0; h < 8; ++h)
        wv[k][c][h] = Wpb[(size_t)(2 * sub + c + 32 * k) * 8 + h] * PAIR_SCALE;

  for (int p = 0; p < 8; ++p) {
    const int r = p * 16 + w * 4 + rg;
    const int j = jt * 128 + r;
    const float* eptr = edge + ((size_t)i * 512 + j) * 128 + 2 * sub;

    float2 e0 = *(const float2*)(eptr);
    float2 e1 = *(const float2*)(eptr + 32);
    float2 e2 = *(const float2*)(eptr + 64);
    float2 e3 = *(const float2*)(eptr + 96);

    float p8[8];
    #pragma unroll
    for (int h = 0; h < 8; ++h)
      p8[h] = e0.x * wv[0][0][h] + e0.y * wv[0][1][h]
            + e1.x * wv[1][0][h] + e1.y * wv[1][1][h]
            + e2.x * wv[2][0][h] + e2.y * wv[2][1][h]
            + e3.x * wv[3][0][h] + e3.y * wv[3][1][h];

    __half2 h0 = __floats2half2_rn(p8[0], p8[1]);
    __half2 h1 = __floats2half2_rn(p8[2], p8[3]);
    __half2 h2 = __floats2half2_rn(p8[4], p8[5]);
    __half2 h3 = __floats2half2_rn(p8[6], p8[7]);
    #pragma unroll
    for (int m = 1; m <= 8; m <<= 1) {
      h0 = __hadd2(h0, shfl_xor_h2(h0, m));
      h1 = __hadd2(h1, shfl_xor_h2(h1, m));
      h2 = __hadd2(h2, shfl_xor_h2(h2, m));
      h3 = __hadd2(h3, shfl_xor_h2(h3, m));
    }
    if (sub == 0) {
      __half* dst = lg16 + ((size_t)i * 512 + j) * 8;
      float4 cur = *(float4*)dst;
      __half2* ch = (__half2*)&cur;
      ch[0] = __hadd2(ch[0], h0);
      ch[1] = __hadd2(ch[1], h1);
      ch[2] = __hadd2(ch[2], h2);
      ch[3] = __hadd2(ch[3], h3);
      *(float4*)dst = cur;
    }
  }
}

// ---------------------------------------------------------------------------
// Kernel B2: softmax -> normalized w[i][j][8] + vs/vp sums + rot/norm.
// 512 blocks (one per i).
// ---------------------------------------------------------------------------
__global__ __launch_bounds__(256) void k_soft(
    const float* __restrict__ rotm, const float* __restrict__ trans,
    const float* __restrict__ ws_r, const __half* __restrict__ lg16,
    float* __restrict__ wout, float* __restrict__ feat)
{
  __shared__ float aw[512 * 12];
  __shared__ float vsp[8 * 128];
  __shared__ float vpp[8 * 96];
  __shared__ float op_l[96];
  __shared__ float rp_l[96];
  __shared__ float linv_l[8];

  const int t = threadIdx.x;
  const int i = blockIdx.x;

  {
    const int lane = t & 63, wid = t >> 6;
    #pragma unroll
    for (int hh = 0; hh < 2; ++hh) {
      int h = wid * 2 + hh;
      float x[8];
      float m = -1e30f;
      #pragma unroll
      for (int r = 0; r < 8; ++r) {
        int j = lane + r * 64;
        x[r] = __half2float(lg16[((size_t)i * 512 + j) * 8 + h]);
        m = fmaxf(m, x[r]);
      }
      #pragma unroll
      for (int s = 32; s; s >>= 1) m = fmaxf(m, __shfl_xor(m, s));
      float ssum = 0.f;
      #pragma unroll
      for (int r = 0; r < 8; ++r) {
        float pv = __expf(x[r] - m);
        ssum += pv;
        aw[(lane + r * 64) * 12 + h] = pv;
      }
      #pragma unroll
      for (int s = 32; s; s >>= 1) ssum += __shfl_xor(ssum, s);
      if (lane == 0) linv_l[h] = 1.0f / ssum;
    }
  }
  __syncthreads();

  // write normalized weights w[i][j][8]
  {
    float4 l0 = *(const float4*)&linv_l[0];
    float4 l1 = *(const float4*)&linv_l[4];
    for (int f = t; f < 1024; f += 256) {
      int j = f >> 1, q = f & 1;
      float4 v = *(const float4*)&aw[j * 12 + q * 4];
      float4 lv = q ? l1 : l0;
      v.x *= lv.x; v.y *= lv.y; v.z *= lv.z; v.w *= lv.w;
      *(float4*)&wout[((size_t)i * 512 + j) * 8 + q * 4] = v;
    }
  }

  // vs / vp weighted sums (L2-resident operands)
  const int dq = t & 31, js = t >> 5;
  const int c0 = dq, c1 = dq + 32, c2 = dq + 64;
  const int h0 = c0 / 12, h1 = c1 / 12, h2 = c2 / 12;
  const int b = dq >> 4;

  float avs[4] = {0,0,0,0};
  float avp[3] = {0,0,0};
  const float* vsg = ws_r + OFF_VS;
  const float* vpg = ws_r + OFF_VP;

  for (int jj = 0; jj < 64; ++jj) {
    int j = js * 64 + jj;
    const float* vr = vsg + (size_t)j * 128 + dq;
    const float* pr = vpg + (size_t)j * 96;
    float4 wlo = *(const float4*)&aw[j * 12];
    float4 whi = *(const float4*)&aw[j * 12 + 4];
    #pragma unroll
    for (int k = 0; k < 4; ++k) {
      float vv = vr[32 * k];
      float wk = (k == 0) ? (b ? wlo.y : wlo.x)
               : (k == 1) ? (b ? wlo.w : wlo.z)
               : (k == 2) ? (b ? whi.y : whi.x)
               :            (b ? whi.w : whi.z);
      avs[k] += wk * vv;
    }
    avp[0] += aw[j * 12 + h0] * pr[c0];
    avp[1] += aw[j * 12 + h1] * pr[c1];
    avp[2] += aw[j * 12 + h2] * pr[c2];
  }

  #pragma unroll
  for (int k = 0; k < 4; ++k) vsp[js * 128 + dq + 32 * k] = avs[k];
  vpp[js * 96 + c0] = avp[0];
  vpp[js * 96 + c1] = avp[1];
  vpp[js * 96 + c2] = avp[2];
  __syncthreads();

  float* frow = feat + (size_t)i * 1280;

  if (t < 128) {
    float s = 0.f;
    #pragma unroll
    for (int q = 0; q < 8; ++q) s += vsp[q * 128 + t];
    frow[t] = s * linv_l[t >> 4];
  }
  if (t < 96) {
    float s = 0.f;
    #pragma unroll
    for (int q = 0; q < 8; ++q) s += vpp[q * 96 + t];
    op_l[t] = s * linv_l[t / 12] - trans[i * 3 + (t % 3)];
  }
  __syncthreads();

  if (t < 96) {
    int c = t % 3, base = t - c;
    const float* R = rotm + (size_t)i * 9;
    float val = op_l[base] * R[c] + op_l[base + 1] * R[3 + c] + op_l[base + 2] * R[6 + c];
    rp_l[t] = val;
    frow[128 + t] = val;
  }
  __syncthreads();
  if (t < 32) {
    float x = rp_l[t * 3], y = rp_l[t * 3 + 1], z = rp_l[t * 3 + 2];
    frow[224 + t] = sqrtf(x * x + y * y + z * z + 1e-8f);
  }
}

// ---------------------------------------------------------------------------
// Kernel B3: res_pair partials. grid (4 jt, 512 i). Coalesced edge pass 2.
// ---------------------------------------------------------------------------
#define FMA4(A, S, E) { A.x += (S)*(E).x; A.y += (S)*(E).y; A.z += (S)*(E).z; A.w += (S)*(E).w; }

__global__ __launch_bounds__(256) void k_rpair(
    const float* __restrict__ edge, const float* __restrict__ ws_r,
    float* __restrict__ ws_w)
{
  __shared__ float4 pl[8][8][32];   // [g][h][dq] 32KB, conflict-free float4
  const int t = threadIdx.x;
  const int jt = blockIdx.x, i = blockIdx.y;
  const int dq = t & 31, g = t >> 5;

  const float* eb = edge + ((size_t)i * 512 + jt * 128) * 128;
  const float* wb = ws_r + OFF_W + ((size_t)i * 512 + jt * 128) * 8;

  float4 acc[8];
  #pragma unroll
  for (int h = 0; h < 8; ++h) acc[h] = {0.f, 0.f, 0.f, 0.f};

  for (int r = 0; r < 16; ++r) {
    int j = g * 16 + r;
    float4 e = *(const float4*)&eb[(size_t)j * 128 + dq * 4];
    float4 w0 = *(const float4*)&wb[j * 8];
    float4 w1 = *(const float4*)&wb[j * 8 + 4];
    FMA4(acc[0], w0.x, e); FMA4(acc[1], w0.y, e);
    FMA4(acc[2], w0.z, e); FMA4(acc[3], w0.w, e);
    FMA4(acc[4], w1.x, e); FMA4(acc[5], w1.y, e);
    FMA4(acc[6], w1.z, e); FMA4(acc[7], w1.w, e);
  }
  #pragma unroll
  for (int h = 0; h < 8; ++h) pl[g][h][dq] = acc[h];
  __syncthreads();

  {
    const int h = t >> 5;
    float4 s = {0.f, 0.f, 0.f, 0.f};
    #pragma unroll
    for (int q = 0; q < 8; ++q) {
      float4 v = pl[q][h][dq];
      s.x += v.x; s.y += v.y; s.z += v.z; s.w += v.w;
    }
    float* dst = ws_w + OFF_RP + (size_t)(i * 4 + jt) * 1024 + h * 128 + dq * 4;
    *(float4*)dst = s;
  }
}

// ---------------------------------------------------------------------------
// Kernel B4: reduce res_pair partials -> feat. 512 blocks.
// ---------------------------------------------------------------------------
__global__ __launch_bounds__(256) void k_rpred(
    const float* __restrict__ ws_r, float* __restrict__ feat)
{
  const int t = threadIdx.x, i = blockIdx.x;
  const int dq = t & 31, h = t >> 5;
  const float* rp = ws_r + OFF_RP + (size_t)i * 4096;
  float4 s = {0.f, 0.f, 0.f, 0.f};
  #pragma unroll
  for (int q = 0; q < 4; ++q) {
    float4 v = *(const float4*)&rp[q * 1024 + h * 128 + dq * 4];
    s.x += v.x; s.y += v.y; s.z += v.z; s.w += v.w;
  }
  *(float4*)&feat[(size_t)i * 1280 + 256 + h * 128 + dq * 4] = s;
}

// ---------------------------------------------------------------------------
// Kernel C1: k-split partial GEMM. grid (16, 8, 4)
// ---------------------------------------------------------------------------
__global__ __launch_bounds__(256) void k_outp(
    const float* __restrict__ feat, const float* __restrict__ Wout,
    float* __restrict__ ws)
{
  __shared__ float As[32 * 33];
  __shared__ float Bs[32 * 36];
  const int t = threadIdx.x;
  const int it = blockIdx.x, ot = blockIdx.y, z = blockIdx.z;
  const int row = t & 31, cb = (t >> 5) * 4;
  float4 acc = {0.f, 0.f, 0.f, 0.f};

  for (int kk = 0; kk < 10; ++kk) {
    int kt = z * 10 + kk;
    __syncthreads();
    #pragma unroll
    for (int q = 0; q < 4; ++q) {
      int f = t + q * 256; int r = f >> 5, c = f & 31;
      As[r * 33 + c] = feat[(size_t)(it * 32 + r) * 1280 + kt * 32 + c];
      Bs[r * 36 + c] = Wout[(size_t)(kt * 32 + r) * 256 + ot * 32 + c];
    }
    __syncthreads();
    #pragma unroll
    for (int k = 0; k < 32; ++k) {
      float a = As[row * 33 + k];
      float4 bv = *(const float4*)&Bs[k * 36 + cb];
      acc.x += a * bv.x; acc.y += a * bv.y; acc.z += a * bv.z; acc.w += a * bv.w;
    }
  }
  float* pc = ws + OFF_OUTP + (size_t)z * 131072;
  *(float4*)&pc[(size_t)(it * 32 + row) * 256 + ot * 32 + cb] = acc;
}

// ---------------------------------------------------------------------------
// Kernel C2: reduce partials + bias. grid 128 x 256.
// ---------------------------------------------------------------------------
__global__ __launch_bounds__(256) void k_outr(
    const float* __restrict__ ws, const float* __restrict__ bout,
    float* __restrict__ out)
{
  const int q = blockIdx.x * 256 + threadIdx.x;
  const float* pc = ws + OFF_OUTP;
  float4 a = *(const float4*)&pc[(size_t)q * 4];
  float4 b = *(const float4*)&pc[(size_t)q * 4 + 131072];
  float4 c = *(const float4*)&pc[(size_t)q * 4 + 262144];
  float4 d = *(const float4*)&pc[(size_t)q * 4 + 393216];
  float4 bias = *(const float4*)&bout[(q & 63) * 4];
  float4 r;
  r.x = a.x + b.x + c.x + d.x + bias.x;
  r.y = a.y + b.y + c.y + d.y + bias.y;
  r.z = a.z + b.z + c.z + d.z + bias.z;
  r.w = a.w + b.w + c.w + d.w + bias.w;
  *(float4*)&out[(size_t)q * 4] = r;
}

// ---------------------------------------------------------------------------
extern "C" void kernel_launch(void* const* d_in, const int* in_sizes, int n_in,
                              void* d_out, int out_size, void* d_ws, size_t ws_size,
                              hipStream_t stream) {
  const float* node  = (const float*)d_in[0];
  const float* edge  = (const float*)d_in[1];
  const float* rotm  = (const float*)d_in[2];
  const float* trans = (const float*)d_in[3];
  const float* Wsq   = (const float*)d_in[4];
  const float* Wsk   = (const float*)d_in[5];
  const float* Wsv   = (const float*)d_in[6];
  const float* Wpq   = (const float*)d_in[7];
  const float* Wpk   = (const float*)d_in[8];
  const float* Wpv   = (const float*)d_in[9];
  const float* pw    = (const float*)d_in[10];
  const float* Wpb   = (const float*)d_in[11];
  const float* bpb   = (const float*)d_in[12];
  const float* Wout  = (const float*)d_in[13];
  const float* bout  = (const float*)d_in[14];
  float* ws   = (float*)d_ws;
  float* out  = (float*)d_out;
  float* feat = ws + OFF_FEAT;
  __half* lg16 = (__half*)(ws + OFF_LG16);

  k_projgemm<<<dim3(16, 21), 256, 0, stream>>>(node, Wsq, Wsk, Wsv, Wpq, Wpk, Wpv, ws);
  k_rot2<<<128, 256, 0, stream>>>(rotm, trans, pw, bpb, ws);
  k_S<<<dim3(16, 16), 256, 0, stream>>>(ws, lg16);
  k_pair<<<dim3(4, 512), 256, 0, stream>>>(edge, Wpb, lg16);
  k_soft<<<512, 256, 0, stream>>>(rotm, trans, ws, lg16, ws + OFF_W, feat);
  k_rpair<<<dim3(4, 512), 256, 0, stream>>>(edge, ws, ws);
  k_rpred<<<512, 256, 0, stream>>>(ws, feat);
  k_outp<<<dim3(16, 8, 4), 256, 0, stream>>>(feat, Wout, ws);
  k_outr<<<128, 256, 0, stream>>>(ws, bout, out);
}

// Round 6
// 127.091 us; speedup vs baseline: 1.0190x; 1.0190x over previous
//
#include <hip/hip_runtime.h>
#include <hip/hip_fp16.h>
#include <math.h>

#define NN 512
#define NODE_D 256
#define EDGE_D 128
#define HN 8

#define SCALAR_SCALE 0.14433756729740643f   // (3*16)^-0.5
#define POINT_SCALE  0.13608276348795434f   // (3*4*4.5)^-0.5
#define PAIR_SCALE   0.5773502691896258f    // 3^-0.5

// workspace float offsets
#define OFF_QS     0            // 512x128
#define OFF_KS     65536        // 512x128
#define OFF_VS     131072       // 512x128
#define OFF_VP     196608       // 512x96
#define OFF_QCAT   245760       // 512x288
#define OFF_KCAT   393216       // 512x288
#define OFF_FEAT   540672       // 512x1280
#define OFF_PRAW   OFF_FEAT     // alias; consumed by k_rot2 before feat written
#define OFF_LG16   1196032      // 512*512*8 halfs = 1048576 float-equiv
#define OFF_EDGE16 2244608      // 512*512*128 halfs = 16777216 float-equiv (64MB)
#define OFF_OUTP   19021824     // 4*512*256 floats
// total ws = 19546112 floats = 78.2 MB (ws is ~512MB per harness poison fill)

// ---------------------------------------------------------------------------
// Kernel A1: Y(512x672) = node @ [Wsq|Wsk|Wsv|Wpq|Wpk|Wpv]. grid (16,21).
// ---------------------------------------------------------------------------
__global__ __launch_bounds__(256) void k_projgemm(
    const float* __restrict__ node,
    const float* __restrict__ Wsq, const float* __restrict__ Wsk, const float* __restrict__ Wsv,
    const float* __restrict__ Wpq, const float* __restrict__ Wpk, const float* __restrict__ Wpv,
    float* __restrict__ ws)
{
  __shared__ float As[32 * 33];
  __shared__ float Bs[32 * 36];
  const int t = threadIdx.x;
  const int it = blockIdx.x;
  const int ct = blockIdx.y;

  const float* W; int ncol, col0; float* dst; int ldd, dcol0;
  if (ct < 12) {
    int a = ct >> 2;
    W = (a == 0) ? Wsq : (a == 1) ? Wsk : Wsv;
    ncol = 128; col0 = (ct & 3) * 32;
    dst = ws + ((a == 0) ? OFF_QS : (a == 1) ? OFF_KS : OFF_VS);
    ldd = 128; dcol0 = col0;
  } else {
    int p = ct - 12;
    int a = p / 3, cc = p % 3;
    W = (a == 0) ? Wpq : (a == 1) ? Wpk : Wpv;
    ncol = 96; col0 = cc * 32;
    dst = ws + OFF_PRAW;
    ldd = 288; dcol0 = a * 96 + cc * 32;
  }

  const int row = t & 31, cb = (t >> 5) * 4;
  float4 acc = {0.f, 0.f, 0.f, 0.f};

  for (int kt = 0; kt < 8; ++kt) {
    __syncthreads();
    #pragma unroll
    for (int q = 0; q < 4; ++q) {
      int f = t + q * 256; int r = f >> 5, c = f & 31;
      As[r * 33 + c] = node[(size_t)(it * 32 + r) * 256 + kt * 32 + c];
      Bs[r * 36 + c] = W[(size_t)(kt * 32 + r) * ncol + col0 + c];
    }
    __syncthreads();
    #pragma unroll
    for (int k = 0; k < 32; ++k) {
      float a = As[row * 33 + k];
      float4 b = *(const float4*)&Bs[k * 36 + cb];
      acc.x += a * b.x; acc.y += a * b.y; acc.z += a * b.z; acc.w += a * b.w;
    }
  }
  *(float4*)&dst[(size_t)(it * 32 + row) * ldd + dcol0 + cb] = acc;
}

// ---------------------------------------------------------------------------
// Kernel A2: rotate/translate points; build Qcat/Kcat (scales folded); vp out.
// ---------------------------------------------------------------------------
__global__ __launch_bounds__(256) void k_rot2(
    const float* __restrict__ rotm, const float* __restrict__ trans,
    const float* __restrict__ pw_in, const float* __restrict__ bpb,
    float* __restrict__ ws)
{
  __shared__ float p_l[4][288];
  __shared__ float r_l[4][288];
  __shared__ float q2_l[4][8];
  __shared__ float k2_l[4][8];
  __shared__ float pw_l[8];
  __shared__ float bpb_l[8];
  const int t = threadIdx.x;
  const int n0 = blockIdx.x * 4;
  const float* praw = ws + OFF_PRAW;
  const float* qs_g = ws + OFF_QS;
  const float* ks_g = ws + OFF_KS;

  if (t < 8) {
    float x = pw_in[t];
    pw_l[t] = 0.5f * POINT_SCALE * logf(1.0f + expf(x));
    bpb_l[t] = bpb[t];
  }
  for (int idx = t; idx < 1152; idx += 256) {
    int row = idx / 288, rem = idx % 288;
    p_l[row][rem] = praw[(size_t)(n0 + row) * 288 + rem];
  }
  __syncthreads();

  for (int idx = t; idx < 1152; idx += 256) {
    int row = idx / 288, rem = idx % 288;
    int a = rem / 96, col = rem % 96;
    int rr = col % 3;
    int n = n0 + row;
    const float* R = rotm + (size_t)(n * 3 + rr) * 3;
    const float* P = &p_l[row][a * 96 + (col - rr)];
    float val = P[0] * R[0] + P[1] * R[1] + P[2] * R[2] + trans[n * 3 + rr];
    r_l[row][a * 96 + col] = val;
    if (a == 2) (ws + OFF_VP)[(size_t)n * 96 + col] = val;
  }
  __syncthreads();

  if (t < 64) {
    int row = t >> 4, rem = t & 15;
    int which = rem >> 3, h = rem & 7;
    const float* src = &r_l[row][which * 96 + h * 12];
    float s = 0.f;
    #pragma unroll
    for (int m = 0; m < 12; ++m) s += src[m] * src[m];
    if (which == 0) q2_l[row][h] = s; else k2_l[row][h] = s;
  }
  __syncthreads();

  for (int idx = t; idx < 2304; idx += 256) {
    int side = idx >= 1152;
    int per = idx - side * 1152;
    int row = per / 288, s = per % 288;
    int h = s / 36, e = s % 36;
    int n = n0 + row;
    float val;
    if (!side) {
      val = (e < 16) ? qs_g[(size_t)n * 128 + h * 16 + e] * SCALAR_SCALE
          : (e < 28) ? 2.0f * pw_l[h] * r_l[row][h * 12 + (e - 16)]
          : (e == 32) ? -pw_l[h]
          : (e == 33) ? (bpb_l[h] * PAIR_SCALE - pw_l[h] * q2_l[row][h])
          : 0.f;
      (ws + OFF_QCAT)[(size_t)n * 288 + s] = val;
    } else {
      val = (e < 16) ? ks_g[(size_t)n * 128 + h * 16 + e]
          : (e < 28) ? r_l[row][96 + h * 12 + (e - 16)]
          : (e == 32) ? k2_l[row][h]
          : (e == 33) ? 1.f
          : 0.f;
      (ws + OFF_KCAT)[(size_t)n * 288 + s] = val;
    }
  }
}

// ---------------------------------------------------------------------------
// Kernel B1a: non-pair logits = batched GEMM lg[i,j,h] = dot36(Qcat,Kcat).
// ---------------------------------------------------------------------------
__global__ __launch_bounds__(256) void k_S(
    const float* __restrict__ ws_c, __half* __restrict__ lg16)
{
  __shared__ float4 Qt[32 * 36];
  __shared__ float4 Kt[32 * 37];
  __shared__ __half lgst[32 * 32 * 8];
  const int t = threadIdx.x;
  const int it = blockIdx.x, jt = blockIdx.y;
  const float* Qc = ws_c + OFF_QCAT;
  const float* Kc = ws_c + OFF_KCAT;
  const int ti = t >> 4, tj = t & 15;

  for (int hg = 0; hg < 2; ++hg) {
    __syncthreads();
    for (int f = t; f < 1152; f += 256) {
      int row = f / 36, c = f % 36;
      Qt[row * 36 + c] = *(const float4*)&Qc[(size_t)(it * 32 + row) * 288 + hg * 144 + c * 4];
      Kt[row * 37 + c] = *(const float4*)&Kc[(size_t)(jt * 32 + row) * 288 + hg * 144 + c * 4];
    }
    __syncthreads();

    float acc[2][2][4];
    #pragma unroll
    for (int a = 0; a < 2; ++a)
      #pragma unroll
      for (int b = 0; b < 2; ++b)
        #pragma unroll
        for (int h = 0; h < 4; ++h) acc[a][b][h] = 0.f;

    for (int c = 0; c < 9; ++c) {
      #pragma unroll
      for (int hh = 0; hh < 4; ++hh) {
        float4 q0 = Qt[(2 * ti + 0) * 36 + hh * 9 + c];
        float4 q1 = Qt[(2 * ti + 1) * 36 + hh * 9 + c];
        float4 k0 = Kt[(2 * tj + 0) * 37 + hh * 9 + c];
        float4 k1 = Kt[(2 * tj + 1) * 37 + hh * 9 + c];
        acc[0][0][hh] += q0.x * k0.x + q0.y * k0.y + q0.z * k0.z + q0.w * k0.w;
        acc[0][1][hh] += q0.x * k1.x + q0.y * k1.y + q0.z * k1.z + q0.w * k1.w;
        acc[1][0][hh] += q1.x * k0.x + q1.y * k0.y + q1.z * k0.z + q1.w * k0.w;
        acc[1][1][hh] += q1.x * k1.x + q1.y * k1.y + q1.z * k1.z + q1.w * k1.w;
      }
    }
    #pragma unroll
    for (int a = 0; a < 2; ++a)
      #pragma unroll
      for (int b = 0; b < 2; ++b)
        #pragma unroll
        for (int hh = 0; hh < 4; ++hh)
          lgst[((2 * ti + a) * 32 + (2 * tj + b)) * 8 + hg * 4 + hh] = __float2half(acc[a][b][hh]);
  }
  __syncthreads();

  for (int f = t; f < 1024; f += 256) {
    int il = f >> 5, jl = f & 31;
    float4 v = *(const float4*)&lgst[(il * 32 + jl) * 8];
    *(float4*)&lg16[((size_t)(it * 32 + il) * 512 + jt * 32 + jl) * 8] = v;
  }
}

// ---------------------------------------------------------------------------
// Kernel B1b: pair logits + fp16 edge copy. grid (4 jt, 512 i).
// Lane sub (16 per row) owns d = 8*sub..8*sub+7 (two float4 loads, one
// 16B half8 store). half2 shuffle reduce over 16 lanes; RMW into lg16.
// ---------------------------------------------------------------------------
static __device__ inline __half2 shfl_xor_h2(__half2 h, int m) {
  int v = __builtin_bit_cast(int, h);
  v = __shfl_xor(v, m);
  return __builtin_bit_cast(__half2, v);
}

__global__ __launch_bounds__(256) void k_pair16(
    const float* __restrict__ edge, const float* __restrict__ Wpb,
    __half* __restrict__ lg16, __half* __restrict__ edge16)
{
  const int t = threadIdx.x;
  const int jt = blockIdx.x, i = blockIdx.y;
  const int l = t & 63, w = t >> 6;
  const int rg = (l >> 4) & 3, sub = l & 15;

  // Wpb slice for d = 8*sub + dd, PAIR_SCALE folded
  float wv[8][8];
  #pragma unroll
  for (int dd = 0; dd < 8; ++dd)
    #pragma unroll
    for (int h = 0; h < 8; ++h)
      wv[dd][h] = Wpb[(size_t)(8 * sub + dd) * 8 + h] * PAIR_SCALE;

  for (int p = 0; p < 8; ++p) {
    const int r = p * 16 + w * 4 + rg;
    const int j = jt * 128 + r;
    const float4* e4 = (const float4*)(edge + ((size_t)i * 512 + j) * 128 + 8 * sub);
    float4 a = e4[0], b = e4[1];

    // fp16 copy (16B contiguous per lane, full 256B row per 16-lane group)
    float4 pk;
    ((__half2*)&pk)[0] = __floats2half2_rn(a.x, a.y);
    ((__half2*)&pk)[1] = __floats2half2_rn(a.z, a.w);
    ((__half2*)&pk)[2] = __floats2half2_rn(b.x, b.y);
    ((__half2*)&pk)[3] = __floats2half2_rn(b.z, b.w);
    *(float4*)(edge16 + ((size_t)i * 512 + j) * 128 + 8 * sub) = pk;

    float e[8] = {a.x, a.y, a.z, a.w, b.x, b.y, b.z, b.w};
    float p8[8];
    #pragma unroll
    for (int h = 0; h < 8; ++h) {
      float s = 0.f;
      #pragma unroll
      for (int dd = 0; dd < 8; ++dd) s += e[dd] * wv[dd][h];
      p8[h] = s;
    }

    __half2 h0 = __floats2half2_rn(p8[0], p8[1]);
    __half2 h1 = __floats2half2_rn(p8[2], p8[3]);
    __half2 h2 = __floats2half2_rn(p8[4], p8[5]);
    __half2 h3 = __floats2half2_rn(p8[6], p8[7]);
    #pragma unroll
    for (int m = 1; m <= 8; m <<= 1) {
      h0 = __hadd2(h0, shfl_xor_h2(h0, m));
      h1 = __hadd2(h1, shfl_xor_h2(h1, m));
      h2 = __hadd2(h2, shfl_xor_h2(h2, m));
      h3 = __hadd2(h3, shfl_xor_h2(h3, m));
    }
    if (sub == 0) {
      __half* dst = lg16 + ((size_t)i * 512 + j) * 8;
      float4 cur = *(float4*)dst;
      __half2* ch = (__half2*)&cur;
      ch[0] = __hadd2(ch[0], h0);
      ch[1] = __hadd2(ch[1], h1);
      ch[2] = __hadd2(ch[2], h2);
      ch[3] = __hadd2(ch[3], h3);
      *(float4*)dst = cur;
    }
  }
}

// ---------------------------------------------------------------------------
// Kernel B2: fused softmax + all attention-weighted outputs (fp16 edge pass).
// 512 blocks (one per i), 256 thr. Thread: dq=t&31 owns d-quad 4dq..4dq+3,
// js=t>>5 owns j in [64js, 64js+64).
// ---------------------------------------------------------------------------
__global__ __launch_bounds__(256) void k_attnout(
    const __half* __restrict__ edge16, const float* __restrict__ rotm,
    const float* __restrict__ trans, const float* __restrict__ ws_r,
    const __half* __restrict__ lg16, float* __restrict__ feat)
{
  __shared__ float awu[8 * 512];    // exp weights [h][512] (16KB); later vsp/vpp
  __shared__ float pl[8][8][128];   // pair partials [js][h][d] (32KB)
  __shared__ float op_l[96];
  __shared__ float rp_l[96];
  __shared__ float linv_l[8];

  const int t = threadIdx.x;
  const int i = blockIdx.x;

  // ---- softmax (2 heads per wave), store unnormalized exp in [h][512] ----
  {
    const int lane = t & 63, wid = t >> 6;
    #pragma unroll
    for (int hh = 0; hh < 2; ++hh) {
      int h = wid * 2 + hh;
      float x[8];
      float m = -1e30f;
      #pragma unroll
      for (int r = 0; r < 8; ++r) {
        int j = lane + r * 64;
        x[r] = __half2float(lg16[((size_t)i * 512 + j) * 8 + h]);
        m = fmaxf(m, x[r]);
      }
      #pragma unroll
      for (int s = 32; s; s >>= 1) m = fmaxf(m, __shfl_xor(m, s));
      float ssum = 0.f;
      #pragma unroll
      for (int r = 0; r < 8; ++r) {
        float pv = __expf(x[r] - m);
        ssum += pv;
        awu[h * 512 + lane + r * 64] = pv;
      }
      #pragma unroll
      for (int s = 32; s; s >>= 1) ssum += __shfl_xor(ssum, s);
      if (lane == 0) linv_l[h] = 1.0f / ssum;
    }
  }
  __syncthreads();

  const int dq = t & 31, js = t >> 5;
  const int hvs = dq >> 2;          // head of vs d-quad
  const int hvp = dq / 3;           // head of vp col-quad (dq<24)

  float acc[8][4];                  // [h][e] pair accumulators
  #pragma unroll
  for (int h = 0; h < 8; ++h)
    #pragma unroll
    for (int e = 0; e < 4; ++e) acc[h][e] = 0.f;
  float avs[4] = {0, 0, 0, 0};
  float avp[4] = {0, 0, 0, 0};

  const float* vsg = ws_r + OFF_VS;
  const float* vpg = ws_r + OFF_VP;

  for (int jj = 0; jj < 64; ++jj) {
    int j = js * 64 + jj;
    uint2 ev = *(const uint2*)(edge16 + ((size_t)i * 512 + j) * 128 + dq * 4);
    __half2 e01 = __builtin_bit_cast(__half2, ev.x);
    __half2 e23 = __builtin_bit_cast(__half2, ev.y);
    float e0 = __low2float(e01), e1 = __high2float(e01);
    float e2 = __low2float(e23), e3 = __high2float(e23);

    float wgt[8];
    #pragma unroll
    for (int h = 0; h < 8; ++h) wgt[h] = awu[h * 512 + j];

    #pragma unroll
    for (int h = 0; h < 8; ++h) {
      acc[h][0] += wgt[h] * e0; acc[h][1] += wgt[h] * e1;
      acc[h][2] += wgt[h] * e2; acc[h][3] += wgt[h] * e3;
    }

    float4 v = *(const float4*)&vsg[(size_t)j * 128 + dq * 4];
    float wv_ = wgt[hvs];
    avs[0] += wv_ * v.x; avs[1] += wv_ * v.y;
    avs[2] += wv_ * v.z; avs[3] += wv_ * v.w;

    if (dq < 24) {
      float4 pv4 = *(const float4*)&vpg[(size_t)j * 96 + dq * 4];
      float wp_ = wgt[hvp];
      avp[0] += wp_ * pv4.x; avp[1] += wp_ * pv4.y;
      avp[2] += wp_ * pv4.z; avp[3] += wp_ * pv4.w;
    }
  }

  // pair partials -> pl[js][h][d] (conflict-free float4 writes)
  #pragma unroll
  for (int h = 0; h < 8; ++h) {
    float4 pv = {acc[h][0], acc[h][1], acc[h][2], acc[h][3]};
    *(float4*)&pl[js][h][dq * 4] = pv;
  }
  __syncthreads();   // all awu reads done; safe to reuse region

  float* vsp = awu;          // [8][128]
  float* vpp = awu + 1024;   // [8][96]
  {
    float4 sv = {avs[0], avs[1], avs[2], avs[3]};
    *(float4*)&vsp[js * 128 + dq * 4] = sv;
    if (dq < 24) {
      float4 pv = {avp[0], avp[1], avp[2], avp[3]};
      *(float4*)&vpp[js * 96 + dq * 4] = pv;
    }
  }
  __syncthreads();

  float* frow = feat + (size_t)i * 1280;

  // ---- reduce pair partials: thread -> (h = t>>5, d-quad = (t&31)*4) ----
  {
    const int h = t >> 5, d4 = (t & 31) * 4;
    float4 s = {0, 0, 0, 0};
    #pragma unroll
    for (int q = 0; q < 8; ++q) {
      float4 v = *(const float4*)&pl[q][h][d4];
      s.x += v.x; s.y += v.y; s.z += v.z; s.w += v.w;
    }
    float li = linv_l[h];
    s.x *= li; s.y *= li; s.z *= li; s.w *= li;
    *(float4*)&frow[256 + h * 128 + d4] = s;
  }
  if (t < 128) {
    float s = 0.f;
    #pragma unroll
    for (int q = 0; q < 8; ++q) s += vsp[q * 128 + t];
    frow[t] = s * linv_l[t >> 4];
  }
  if (t < 96) {
    float s = 0.f;
    #pragma unroll
    for (int q = 0; q < 8; ++q) s += vpp[q * 96 + t];
    op_l[t] = s * linv_l[t / 12] - trans[i * 3 + (t % 3)];
  }
  __syncthreads();

  if (t < 96) {
    int c = t % 3, base = t - c;
    const float* R = rotm + (size_t)i * 9;
    float val = op_l[base] * R[c] + op_l[base + 1] * R[3 + c] + op_l[base + 2] * R[6 + c];
    rp_l[t] = val;
    frow[128 + t] = val;
  }
  __syncthreads();
  if (t < 32) {
    float x = rp_l[t * 3], y = rp_l[t * 3 + 1], z = rp_l[t * 3 + 2];
    frow[224 + t] = sqrtf(x * x + y * y + z * z + 1e-8f);
  }
}

// ---------------------------------------------------------------------------
// Kernel C1: k-split partial GEMM. grid (16, 8, 4)
// ---------------------------------------------------------------------------
__global__ __launch_bounds__(256) void k_outp(
    const float* __restrict__ feat, const float* __restrict__ Wout,
    float* __restrict__ ws)
{
  __shared__ float As[32 * 33];
  __shared__ float Bs[32 * 36];
  const int t = threadIdx.x;
  const int it = blockIdx.x, ot = blockIdx.y, z = blockIdx.z;
  const int row = t & 31, cb = (t >> 5) * 4;
  float4 acc = {0.f, 0.f, 0.f, 0.f};

  for (int kk = 0; kk < 10; ++kk) {
    int kt = z * 10 + kk;
    __syncthreads();
    #pragma unroll
    for (int q = 0; q < 4; ++q) {
      int f = t + q * 256; int r = f >> 5, c = f & 31;
      As[r * 33 + c] = feat[(size_t)(it * 32 + r) * 1280 + kt * 32 + c];
      Bs[r * 36 + c] = Wout[(size_t)(kt * 32 + r) * 256 + ot * 32 + c];
    }
    __syncthreads();
    #pragma unroll
    for (int k = 0; k < 32; ++k) {
      float a = As[row * 33 + k];
      float4 bv = *(const float4*)&Bs[k * 36 + cb];
      acc.x += a * bv.x; acc.y += a * bv.y; acc.z += a * bv.z; acc.w += a * bv.w;
    }
  }
  float* pc = ws + OFF_OUTP + (size_t)z * 131072;
  *(float4*)&pc[(size_t)(it * 32 + row) * 256 + ot * 32 + cb] = acc;
}

// ---------------------------------------------------------------------------
// Kernel C2: reduce partials + bias. grid 128 x 256.
// ---------------------------------------------------------------------------
__global__ __launch_bounds__(256) void k_outr(
    const float* __restrict__ ws, const float* __restrict__ bout,
    float* __restrict__ out)
{
  const int q = blockIdx.x * 256 + threadIdx.x;
  const float* pc = ws + OFF_OUTP;
  float4 a = *(const float4*)&pc[(size_t)q * 4];
  float4 b = *(const float4*)&pc[(size_t)q * 4 + 131072];
  float4 c = *(const float4*)&pc[(size_t)q * 4 + 262144];
  float4 d = *(const float4*)&pc[(size_t)q * 4 + 393216];
  float4 bias = *(const float4*)&bout[(q & 63) * 4];
  float4 r;
  r.x = a.x + b.x + c.x + d.x + bias.x;
  r.y = a.y + b.y + c.y + d.y + bias.y;
  r.z = a.z + b.z + c.z + d.z + bias.z;
  r.w = a.w + b.w + c.w + d.w + bias.w;
  *(float4*)&out[(size_t)q * 4] = r;
}

// ---------------------------------------------------------------------------
extern "C" void kernel_launch(void* const* d_in, const int* in_sizes, int n_in,
                              void* d_out, int out_size, void* d_ws, size_t ws_size,
                              hipStream_t stream) {
  const float* node  = (const float*)d_in[0];
  const float* edge  = (const float*)d_in[1];
  const float* rotm  = (const float*)d_in[2];
  const float* trans = (const float*)d_in[3];
  const float* Wsq   = (const float*)d_in[4];
  const float* Wsk   = (const float*)d_in[5];
  const float* Wsv   = (const float*)d_in[6];
  const float* Wpq   = (const float*)d_in[7];
  const float* Wpk   = (const float*)d_in[8];
  const float* Wpv   = (const float*)d_in[9];
  const float* pw    = (const float*)d_in[10];
  const float* Wpb   = (const float*)d_in[11];
  const float* bpb   = (const float*)d_in[12];
  const float* Wout  = (const float*)d_in[13];
  const float* bout  = (const float*)d_in[14];
  float* ws   = (float*)d_ws;
  float* out  = (float*)d_out;
  float* feat = ws + OFF_FEAT;
  __half* lg16   = (__half*)(ws + OFF_LG16);
  __half* edge16 = (__half*)(ws + OFF_EDGE16);

  k_projgemm<<<dim3(16, 21), 256, 0, stream>>>(node, Wsq, Wsk, Wsv, Wpq, Wpk, Wpv, ws);
  k_rot2<<<128, 256, 0, stream>>>(rotm, trans, pw, bpb, ws);
  k_S<<<dim3(16, 16), 256, 0, stream>>>(ws, lg16);
  k_pair16<<<dim3(4, 512), 256, 0, stream>>>(edge, Wpb, lg16, edge16);
  k_attnout<<<512, 256, 0, stream>>>(edge16, rotm, trans, ws, lg16, feat);
  k_outp<<<dim3(16, 8, 4), 256, 0, stream>>>(feat, Wout, ws);
  k_outr<<<128, 256, 0, stream>>>(ws, bout, out);
}